// Round 4
// baseline (657.769 us; speedup 1.0000x reference)
//
#include <hip/hip_runtime.h>
#include <cstdint>
#include <cstddef>

#define ALPHA 0.2f
// N=8192, Fin=512, Fout=256 hard-coded per problem instance.

typedef __attribute__((ext_vector_type(8)))  short short8;   // 8 bf16 (4 VGPRs)
typedef __attribute__((ext_vector_type(16))) float f32x16;   // 32x32 MFMA acc

static __device__ __forceinline__ unsigned short f2bf(float x) {
  union { float f; unsigned u; } c; c.f = x;
  unsigned u = c.u;
  return (unsigned short)((u + 0x7FFFu + ((u >> 16) & 1u)) >> 16);  // RNE
}
// pack hi16(round-half-up) of two floats: result = bf(b)<<16 | bf(a)
static __device__ __forceinline__ unsigned pack_bf2(float a, float b) {
  return __builtin_amdgcn_perm(__float_as_uint(b) + 0x8000u,
                               __float_as_uint(a) + 0x8000u, 0x07060302u);
}

// ---------------- Kernel A: Whp = h @ W, K-split x2 (fp32) ------------------
__global__ __launch_bounds__(256, 2) void gemm1(const float* __restrict__ h,
                                                const float* __restrict__ W,
                                                float* __restrict__ Whp) {
  __shared__ float As[32][132];
  __shared__ float Bs[32][64];
  const int t = threadIdx.x;
  const int bid = blockIdx.x;
  const int nb = bid & 3, kb = (bid >> 2) & 1, mb = bid >> 3;
  const int m0 = mb * 128, n0 = nb * 64, kbase = kb * 256;
  const int ty = t >> 4, tx = t & 15;
  float acc[8][4];
#pragma unroll
  for (int i = 0; i < 8; i++)
#pragma unroll
    for (int j = 0; j < 4; j++) acc[i][j] = 0.f;

  for (int k0 = kbase; k0 < kbase + 256; k0 += 32) {
#pragma unroll
    for (int c = 0; c < 4; c++) {
      int m = c * 32 + (t >> 3);
      int kq = (t & 7) * 4;
      float4 v = *(const float4*)&h[(size_t)(m0 + m) * 512 + k0 + kq];
      As[kq + 0][m] = v.x; As[kq + 1][m] = v.y;
      As[kq + 2][m] = v.z; As[kq + 3][m] = v.w;
    }
#pragma unroll
    for (int c = 0; c < 2; c++) {
      int k = c * 16 + (t >> 4);
      int n = (t & 15) * 4;
      *(float4*)&Bs[k][n] = *(const float4*)&W[(size_t)(k0 + k) * 256 + n0 + n];
    }
    __syncthreads();
#pragma unroll
    for (int k = 0; k < 32; k++) {
      float4 a0 = *(float4*)&As[k][ty * 8];
      float4 a1 = *(float4*)&As[k][ty * 8 + 4];
      float4 b  = *(float4*)&Bs[k][tx * 4];
      float av[8] = {a0.x, a0.y, a0.z, a0.w, a1.x, a1.y, a1.z, a1.w};
      float bv[4] = {b.x, b.y, b.z, b.w};
#pragma unroll
      for (int i = 0; i < 8; i++)
#pragma unroll
        for (int j = 0; j < 4; j++) acc[i][j] = fmaf(av[i], bv[j], acc[i][j]);
    }
    __syncthreads();
  }
  float* dst = Whp + (size_t)kb * (8192 * 256);
#pragma unroll
  for (int i = 0; i < 8; i++) {
    float4 v = {acc[i][0], acc[i][1], acc[i][2], acc[i][3]};
    *(float4*)&dst[(size_t)(m0 + ty * 8 + i) * 256 + n0 + tx * 4] = v;
  }
}

// ------- Kernel B: per-row f1,f2 dots, u/v pack, f2max via atomicMax --------
__global__ __launch_bounds__(256) void rowstats(const float* __restrict__ Whp,
                                                const float* __restrict__ a,
                                                float* __restrict__ f1,
                                                unsigned* __restrict__ uvpack,
                                                unsigned* __restrict__ f2key) {
  const int t = threadIdx.x;
  const int w = t >> 6, lane = t & 63;
  const int i = blockIdx.x * 4 + w;
  const size_t off = (size_t)i * 256 + lane * 4;
  float4 v0 = *(const float4*)&Whp[off];
  float4 v1 = *(const float4*)&Whp[(size_t)8192 * 256 + off];
  float4 wv = {v0.x + v1.x, v0.y + v1.y, v0.z + v1.z, v0.w + v1.w};
  float4 a1 = *(const float4*)&a[lane * 4];
  float4 a2 = *(const float4*)&a[256 + lane * 4];
  float s1 = wv.x * a1.x + wv.y * a1.y + wv.z * a1.z + wv.w * a1.w;
  float s2 = wv.x * a2.x + wv.y * a2.y + wv.z * a2.z + wv.w * a2.w;
#pragma unroll
  for (int o = 32; o; o >>= 1) { s1 += __shfl_xor(s1, o); s2 += __shfl_xor(s2, o); }
  if (lane == 0) {
    f1[i] = s1;
    // u = exp(f2) in LOW 16 (consumer does pk<<16), v = exp(0.2 f2) in HIGH
    float u = __expf(s2), v = __expf(ALPHA * s2);
    uvpack[i] = (unsigned)f2bf(u) | ((unsigned)f2bf(v) << 16);
    unsigned ub = __float_as_uint(s2);
    unsigned key = (ub & 0x80000000u) ? ~ub : (ub | 0x80000000u);
    atomicMax(f2key, key);
  }
}

// --------- Kernel B2: WhT[c][i] bf16 transpose, column-thread stream --------
__global__ __launch_bounds__(256) void transpose_k(const float* __restrict__ Whp,
                                                   unsigned short* __restrict__ WhT) {
  const int c = threadIdx.x;
  const int i0 = blockIdx.x * 32;
  const float* p0 = Whp + (size_t)i0 * 256 + c;
  const float* p1 = p0 + (size_t)8192 * 256;
#pragma unroll
  for (int ii = 0; ii < 32; ii += 8) {
    unsigned pk[4];
#pragma unroll
    for (int x = 0; x < 4; x++) {
      float s0 = p0[(ii + 2 * x) * 256] + p1[(ii + 2 * x) * 256];
      float s1 = p0[(ii + 2 * x + 1) * 256] + p1[(ii + 2 * x + 1) * 256];
      pk[x] = pack_bf2(s0, s1);
    }
    uint4 q; q.x = pk[0]; q.y = pk[1]; q.z = pk[2]; q.w = pk[3];
    *(uint4*)&WhT[(size_t)c * 8192 + i0 + ii] = q;
  }
}

// --------- Kernel B3: adj (int32, 268MB) -> bitmask (8MB), pure stream ------
// wave per row; 128 uint64 words per row (8192 cols). FIX R3: loop covered
// only words 0..31 (j<2048), leaving 75% of mask poisoned -> absmax 1.34.
__global__ __launch_bounds__(256) void adj_compress(const int* __restrict__ adj,
    unsigned long long* __restrict__ mask) {
  const int wave = threadIdx.x >> 6, lane = threadIdx.x & 63;
  const int row = blockIdx.x * 4 + wave;
  const int* ap = adj + (size_t)row * 8192 + lane;
  unsigned long long* mp = mask + (size_t)row * 128;
  for (int i0 = 0; i0 < 128; i0 += 8) {
    int v[8];
#pragma unroll
    for (int k = 0; k < 8; k++) v[k] = ap[(i0 + k) * 64];   // 8 loads in flight
#pragma unroll
    for (int k = 0; k < 8; k++) {
      unsigned long long m = __ballot(v[k] > 0);
      if (lane == 0) mp[i0 + k] = m;
    }
  }
}

// ---------------- Kernel C: barrier-free fused masked-softmax @ Wh ----------
// Wave owns 32 rows x 128 cols x j-slice. A-frags (P) built in registers in
// MFMA A layout: lane(am,asel) = row am, k = asel*8+jj. No LDS P, no barriers
// after the one-time uvs preload. 4 waves/block = 2 row-tiles x 2 col-tiles.
template <int JW>
__global__ __launch_bounds__(256, 3) void attn_main(
    const unsigned char* __restrict__ mask, const float* __restrict__ f1p,
    const unsigned* __restrict__ uvpack, const unsigned short* __restrict__ WhT,
    const unsigned* __restrict__ f2key, float* __restrict__ accP,
    float* __restrict__ lP) {
  constexpr int JS = 8192 / JW;
  constexpr int G = JW / 64;
  __shared__ unsigned uvs[JW];
  const int t = threadIdx.x;
  const int bid = blockIdx.x;
  const int js = bid % JS, rg = bid / JS;
  const int wave = t >> 6, lane = t & 63;
  const int rt = wave >> 1, ct = wave & 1;
  const int am = lane & 31, asel = lane >> 5;
  const int r0 = rg * 64 + rt * 32;
  const int c0 = ct * 128;
  const int jbase = js * JW;

#pragma unroll
  for (int c = 0; c < JW / 1024; c++) {
    int idx = c * 1024 + t * 4;
    *(uint4*)&uvs[idx] = *(const uint4*)&uvpack[jbase + idx];
  }
  __syncthreads();   // the only barrier

  unsigned key = *f2key;
  unsigned ub = (key & 0x80000000u) ? (key & 0x7FFFFFFFu) : ~key;
  const float F2max = __uint_as_float(ub);
  const float f1v = f1p[r0 + am];            // row consts are lane-resident
  const float x = f1v + F2max;
  const float M = x > 0.f ? x : ALPHA * x;   // analytic per-row max bound
  const float Ai = __expf(f1v - M);
  const float Bi = __expf(ALPHA * f1v - M);
  const float Ui = __expf(-f1v);             // u_j > Ui <=> f1_i + f2_j > 0

  f32x16 acc0 = {}, acc1 = {}, acc2 = {}, acc3 = {};
  float ls0 = 0.f, ls1 = 0.f;
  const int sh = asel * 8;

  const unsigned char* mrow = mask + (size_t)(r0 + am) * 1024 + (jbase >> 3);
  const unsigned short* bbase = WhT + (size_t)(c0 + am) * 8192 + jbase + asel * 8;

  uint2 mm = *(const uint2*)mrow;
  for (int g = 0; g < G; g++) {
    uint2 mmn = {0u, 0u};
    if (g + 1 < G) mmn = *(const uint2*)(mrow + (size_t)(g + 1) * 8);  // HBM prefetch
#pragma unroll
    for (int k = 0; k < 4; k++) {
      const int jl = g * 64 + k * 16;
      uint4 uv0 = *(const uint4*)&uvs[jl + asel * 8];       // wave-uniform: broadcast
      uint4 uv1 = *(const uint4*)&uvs[jl + asel * 8 + 4];
      short8 bf0 = *(const short8*)(bbase + jl);
      short8 bf1 = *(const short8*)(bbase + (size_t)1 * 32 * 8192 + jl);
      short8 bf2 = *(const short8*)(bbase + (size_t)2 * 32 * 8192 + jl);
      short8 bf3 = *(const short8*)(bbase + (size_t)3 * 32 * 8192 + jl);
      unsigned mw = (k < 2) ? mm.x : mm.y;
      unsigned mbyte = (mw >> ((k & 1) * 16 + sh)) & 0xFFu;
      const unsigned uva[8] = {uv0.x, uv0.y, uv0.z, uv0.w, uv1.x, uv1.y, uv1.z, uv1.w};
      float w[8];
#pragma unroll
      for (int jj = 0; jj < 8; jj++) {
        float u = __uint_as_float(uva[jj] << 16);          // exp(f2_j)
        float v = __uint_as_float(uva[jj] & 0xFFFF0000u);  // exp(0.2 f2_j)
        float sel = (u > Ui) ? Ai * u : Bi * v;            // exp(leaky(f1+f2)-M)
        w[jj] = (mbyte & (1u << jj)) ? sel : 0.f;
      }
      ls0 += (w[0] + w[1]) + (w[2] + w[3]);
      ls1 += (w[4] + w[5]) + (w[6] + w[7]);
      union { short8 s; unsigned u[4]; } af;
      af.u[0] = pack_bf2(w[0], w[1]); af.u[1] = pack_bf2(w[2], w[3]);
      af.u[2] = pack_bf2(w[4], w[5]); af.u[3] = pack_bf2(w[6], w[7]);
      acc0 = __builtin_amdgcn_mfma_f32_32x32x16_bf16(af.s, bf0, acc0, 0, 0, 0);
      acc1 = __builtin_amdgcn_mfma_f32_32x32x16_bf16(af.s, bf1, acc1, 0, 0, 0);
      acc2 = __builtin_amdgcn_mfma_f32_32x32x16_bf16(af.s, bf2, acc2, 0, 0, 0);
      acc3 = __builtin_amdgcn_mfma_f32_32x32x16_bf16(af.s, bf3, acc3, 0, 0, 0);
    }
    mm = mmn;
  }

  float lsum = ls0 + ls1;
  lsum += __shfl_xor(lsum, 32);
  const size_t base = (size_t)js * (8192 * 256);
  const f32x16* accs[4] = {&acc0, &acc1, &acc2, &acc3};
#pragma unroll
  for (int tt = 0; tt < 4; tt++) {
#pragma unroll
    for (int reg = 0; reg < 16; reg++) {
      const int row = r0 + (reg & 3) + 8 * (reg >> 2) + 4 * asel;  // verified C/D map
      const int col = c0 + tt * 32 + am;
      accP[base + (size_t)row * 256 + col] = (*accs[tt])[reg];
    }
  }
  if (ct == 0 && asel == 0) lP[(size_t)js * 8192 + r0 + am] = lsum;
}

// ---------------- Kernel D: combine slices, normalize, ELU ------------------
__global__ __launch_bounds__(256) void combine(const float* __restrict__ accP,
                                               const float* __restrict__ lP,
                                               float* __restrict__ out, int JS) {
  const int idx = (blockIdx.x * 256 + threadIdx.x) * 4;
  const int row = idx >> 8;
  float4 s = {0.f, 0.f, 0.f, 0.f};
  float l = 0.f;
  for (int j = 0; j < JS; j++) {
    float4 a = *(const float4*)&accP[(size_t)j * (8192 * 256) + idx];
    s.x += a.x; s.y += a.y; s.z += a.z; s.w += a.w;
    l += lP[(size_t)j * 8192 + row];
  }
  float inv = 1.0f / fmaxf(l, 1e-30f);
  float vv[4] = {s.x * inv, s.y * inv, s.z * inv, s.w * inv};
  float4 o;
  o.x = vv[0] > 0.f ? vv[0] : __expf(vv[0]) - 1.f;
  o.y = vv[1] > 0.f ? vv[1] : __expf(vv[1]) - 1.f;
  o.z = vv[2] > 0.f ? vv[2] : __expf(vv[2]) - 1.f;
  o.w = vv[3] > 0.f ? vv[3] : __expf(vv[3]) - 1.f;
  *(float4*)&out[idx] = o;
}

extern "C" void kernel_launch(void* const* d_in, const int* in_sizes, int n_in,
                              void* d_out, int out_size, void* d_ws, size_t ws_size,
                              hipStream_t stream) {
  const float* h  = (const float*)d_in[0];
  const int* adj  = (const int*)d_in[1];
  const float* W  = (const float*)d_in[2];
  const float* a  = (const float*)d_in[3];
  char* ws = (char*)d_ws;
  const size_t NF = (size_t)8192 * 256;

  // JS by workspace: JS8 needs 64M accP + 4M WhT + 8M mask + smalls (~77M).
  const int JS = (ws_size >= ((size_t)78 << 20)) ? 8
               : (ws_size >= ((size_t)46 << 20)) ? 4 : 2;

  // layout: [0, JS*8M) accP (Whp 16M aliases its head, dead before attn);
  // then WhT 4M, mask 8M, smalls.
  float* Whp                = (float*)ws;
  float* accP               = (float*)ws;
  const size_t accB         = (size_t)JS * NF * 4;
  unsigned short* WhT       = (unsigned short*)(ws + accB);
  unsigned long long* maskp = (unsigned long long*)(ws + accB + ((size_t)4 << 20));
  char* sm                  = ws + accB + ((size_t)12 << 20);
  float* f1                 = (float*)sm;
  unsigned* uvpack          = (unsigned*)(sm + (32 << 10));
  unsigned* f2key           = (unsigned*)(sm + (64 << 10));
  float* lP                 = (float*)(sm + (68 << 10));

  hipMemsetAsync(f2key, 0, 4, stream);
  gemm1<<<512, 256, 0, stream>>>(h, W, Whp);
  transpose_k<<<256, 256, 0, stream>>>(Whp, WhT);
  rowstats<<<2048, 256, 0, stream>>>(Whp, a, f1, uvpack, f2key);
  adj_compress<<<2048, 256, 0, stream>>>(adj, maskp);
  if (JS == 8)
    attn_main<1024><<<1024, 256, 0, stream>>>((const unsigned char*)maskp, f1, uvpack, WhT, f2key, accP, lP);
  else if (JS == 4)
    attn_main<2048><<<512, 256, 0, stream>>>((const unsigned char*)maskp, f1, uvpack, WhT, f2key, accP, lP);
  else
    attn_main<4096><<<256, 256, 0, stream>>>((const unsigned char*)maskp, f1, uvpack, WhT, f2key, accP, lP);
  combine<<<2048, 256, 0, stream>>>(accP, lP, (float*)d_out, JS);
}

// Round 5
// 655.247 us; speedup vs baseline: 1.0038x; 1.0038x over previous
//
#include <hip/hip_runtime.h>
#include <cstdint>
#include <cstddef>

#define ALPHA 0.2f
// N=8192, Fin=512, Fout=256 hard-coded per problem instance.

typedef __attribute__((ext_vector_type(8)))  short short8;   // 8 bf16 (4 VGPRs)
typedef __attribute__((ext_vector_type(16))) float f32x16;   // 32x32 MFMA acc

static __device__ __forceinline__ unsigned short f2bf(float x) {
  union { float f; unsigned u; } c; c.f = x;
  unsigned u = c.u;
  return (unsigned short)((u + 0x7FFFu + ((u >> 16) & 1u)) >> 16);  // RNE
}
// pack hi16(round-half-up) of two floats: result = bf(b)<<16 | bf(a)
static __device__ __forceinline__ unsigned pack_bf2(float a, float b) {
  return __builtin_amdgcn_perm(__float_as_uint(b) + 0x8000u,
                               __float_as_uint(a) + 0x8000u, 0x07060302u);
}

// ---------------- Kernel A: Whp = h @ W, K-split x2 (fp32) ------------------
__global__ __launch_bounds__(256, 2) void gemm1(const float* __restrict__ h,
                                                const float* __restrict__ W,
                                                float* __restrict__ Whp) {
  __shared__ float As[32][132];
  __shared__ float Bs[32][64];
  const int t = threadIdx.x;
  const int bid = blockIdx.x;
  const int nb = bid & 3, kb = (bid >> 2) & 1, mb = bid >> 3;
  const int m0 = mb * 128, n0 = nb * 64, kbase = kb * 256;
  const int ty = t >> 4, tx = t & 15;
  float acc[8][4];
#pragma unroll
  for (int i = 0; i < 8; i++)
#pragma unroll
    for (int j = 0; j < 4; j++) acc[i][j] = 0.f;

  for (int k0 = kbase; k0 < kbase + 256; k0 += 32) {
#pragma unroll
    for (int c = 0; c < 4; c++) {
      int m = c * 32 + (t >> 3);
      int kq = (t & 7) * 4;
      float4 v = *(const float4*)&h[(size_t)(m0 + m) * 512 + k0 + kq];
      As[kq + 0][m] = v.x; As[kq + 1][m] = v.y;
      As[kq + 2][m] = v.z; As[kq + 3][m] = v.w;
    }
#pragma unroll
    for (int c = 0; c < 2; c++) {
      int k = c * 16 + (t >> 4);
      int n = (t & 15) * 4;
      *(float4*)&Bs[k][n] = *(const float4*)&W[(size_t)(k0 + k) * 256 + n0 + n];
    }
    __syncthreads();
#pragma unroll
    for (int k = 0; k < 32; k++) {
      float4 a0 = *(float4*)&As[k][ty * 8];
      float4 a1 = *(float4*)&As[k][ty * 8 + 4];
      float4 b  = *(float4*)&Bs[k][tx * 4];
      float av[8] = {a0.x, a0.y, a0.z, a0.w, a1.x, a1.y, a1.z, a1.w};
      float bv[4] = {b.x, b.y, b.z, b.w};
#pragma unroll
      for (int i = 0; i < 8; i++)
#pragma unroll
        for (int j = 0; j < 4; j++) acc[i][j] = fmaf(av[i], bv[j], acc[i][j]);
    }
    __syncthreads();
  }
  float* dst = Whp + (size_t)kb * (8192 * 256);
#pragma unroll
  for (int i = 0; i < 8; i++) {
    float4 v = {acc[i][0], acc[i][1], acc[i][2], acc[i][3]};
    *(float4*)&dst[(size_t)(m0 + ty * 8 + i) * 256 + n0 + tx * 4] = v;
  }
}

// ------- Kernel B: per-row f1,f2 dots, u/v pack, f2max via atomicMax --------
__global__ __launch_bounds__(256) void rowstats(const float* __restrict__ Whp,
                                                const float* __restrict__ a,
                                                float* __restrict__ f1,
                                                unsigned* __restrict__ uvpack,
                                                unsigned* __restrict__ f2key) {
  const int t = threadIdx.x;
  const int w = t >> 6, lane = t & 63;
  const int i = blockIdx.x * 4 + w;
  const size_t off = (size_t)i * 256 + lane * 4;
  float4 v0 = *(const float4*)&Whp[off];
  float4 v1 = *(const float4*)&Whp[(size_t)8192 * 256 + off];
  float4 wv = {v0.x + v1.x, v0.y + v1.y, v0.z + v1.z, v0.w + v1.w};
  float4 a1 = *(const float4*)&a[lane * 4];
  float4 a2 = *(const float4*)&a[256 + lane * 4];
  float s1 = wv.x * a1.x + wv.y * a1.y + wv.z * a1.z + wv.w * a1.w;
  float s2 = wv.x * a2.x + wv.y * a2.y + wv.z * a2.z + wv.w * a2.w;
#pragma unroll
  for (int o = 32; o; o >>= 1) { s1 += __shfl_xor(s1, o); s2 += __shfl_xor(s2, o); }
  if (lane == 0) {
    f1[i] = s1;
    // u = exp(f2) in LOW 16 (consumer does pk<<16), v = exp(0.2 f2) in HIGH
    float u = __expf(s2), v = __expf(ALPHA * s2);
    uvpack[i] = (unsigned)f2bf(u) | ((unsigned)f2bf(v) << 16);
    unsigned ub = __float_as_uint(s2);
    unsigned key = (ub & 0x80000000u) ? ~ub : (ub | 0x80000000u);
    atomicMax(f2key, key);
  }
}

// --------- Kernel B2: WhT[c][i] bf16 transpose, column-thread stream --------
__global__ __launch_bounds__(256) void transpose_k(const float* __restrict__ Whp,
                                                   unsigned short* __restrict__ WhT) {
  const int c = threadIdx.x;
  const int i0 = blockIdx.x * 32;
  const float* p0 = Whp + (size_t)i0 * 256 + c;
  const float* p1 = p0 + (size_t)8192 * 256;
#pragma unroll
  for (int ii = 0; ii < 32; ii += 8) {
    unsigned pk[4];
#pragma unroll
    for (int x = 0; x < 4; x++) {
      float s0 = p0[(ii + 2 * x) * 256] + p1[(ii + 2 * x) * 256];
      float s1 = p0[(ii + 2 * x + 1) * 256] + p1[(ii + 2 * x + 1) * 256];
      pk[x] = pack_bf2(s0, s1);
    }
    uint4 q; q.x = pk[0]; q.y = pk[1]; q.z = pk[2]; q.w = pk[3];
    *(uint4*)&WhT[(size_t)c * 8192 + i0 + ii] = q;
  }
}

// --------- Kernel B3: adj (int32, 268MB) -> bitmask (8MB), pure stream ------
__global__ __launch_bounds__(256) void adj_compress(const int* __restrict__ adj,
    unsigned long long* __restrict__ mask) {
  const int wave = threadIdx.x >> 6, lane = threadIdx.x & 63;
  const int row = blockIdx.x * 4 + wave;
  const int* ap = adj + (size_t)row * 8192 + lane;
  unsigned long long* mp = mask + (size_t)row * 128;
  for (int i0 = 0; i0 < 128; i0 += 8) {
    int v[8];
#pragma unroll
    for (int k = 0; k < 8; k++) v[k] = ap[(i0 + k) * 64];   // 8 loads in flight
#pragma unroll
    for (int k = 0; k < 8; k++) {
      unsigned long long m = __ballot(v[k] > 0);
      if (lane == 0) mp[i0 + k] = m;
    }
  }
}

// ---------------- Kernel C: barrier-free fused masked-softmax @ Wh ----------
// One wave per block; wave owns 32 rows x ALL 256 cols x j-slice (8 MFMA
// tiles). A-frag built once per (row-tile, kstep) — no ct redundancy. No LDS,
// no barriers. B-frags + uv double-buffered in registers one kstep ahead
// (8 b128 in flight over the VALU A-build). uvpack slice is L1-resident.
template <int JW>
__global__ __launch_bounds__(64, 2) void attn_main(
    const unsigned char* __restrict__ mask, const float* __restrict__ f1p,
    const unsigned* __restrict__ uvpack, const unsigned short* __restrict__ WhT,
    const unsigned* __restrict__ f2key, float* __restrict__ accP,
    float* __restrict__ lP) {
  constexpr int JS = 8192 / JW;
  constexpr int NK = JW / 16;          // ksteps of 16 j
  const int bid = blockIdx.x;
  const int js = bid % JS, rt = bid / JS;
  const int lane = threadIdx.x & 63;
  const int am = lane & 31, asel = lane >> 5;
  const int r0 = rt * 32;
  const int jbase = js * JW;
  const int sh = asel * 8;

  unsigned key = *f2key;
  unsigned ub = (key & 0x80000000u) ? (key & 0x7FFFFFFFu) : ~key;
  const float F2max = __uint_as_float(ub);
  const float f1v = f1p[r0 + am];            // row consts lane-resident
  const float x = f1v + F2max;
  const float M = x > 0.f ? x : ALPHA * x;   // analytic per-row max bound
  const float Ai = __expf(f1v - M);
  const float Bi = __expf(ALPHA * f1v - M);
  const float Ui = __expf(-f1v);             // u_j > Ui <=> f1_i + f2_j > 0

  const unsigned short* bbase = WhT + (size_t)am * 8192 + jbase + asel * 8;
  const unsigned* uvp = uvpack + jbase + asel * 8;
  const unsigned char* mrow = mask + (size_t)(r0 + am) * 1024 + (jbase >> 3);

  f32x16 acc[8] = {};
  short8 b[2][8];
  uint4 uvA[2], uvB[2];
  float ls = 0.f;

#pragma unroll
  for (int tt = 0; tt < 8; tt++)
    b[0][tt] = *(const short8*)(bbase + (size_t)tt * 32 * 8192);
  uvA[0] = *(const uint4*)(uvp);
  uvB[0] = *(const uint4*)(uvp + 4);
  uint2 mm = *(const uint2*)mrow;

  for (int g = 0; g < NK / 4; g++) {
    // mask prefetch (last iter over-reads into next row's mask — in-bounds)
    uint2 mmn = *(const uint2*)(mrow + (size_t)(g + 1) * 8);
#pragma unroll
    for (int k = 0; k < 4; k++) {
      const int s = g * 4 + k;
      const int cur = k & 1, nxt = cur ^ 1;
      // prefetch kstep s+1 (final over-read lands in-bounds of ws)
      const unsigned short* bn = bbase + (size_t)(s + 1) * 16;
#pragma unroll
      for (int tt = 0; tt < 8; tt++)
        b[nxt][tt] = *(const short8*)(bn + (size_t)tt * 32 * 8192);
      uvA[nxt] = *(const uint4*)(uvp + (s + 1) * 16);
      uvB[nxt] = *(const uint4*)(uvp + (s + 1) * 16 + 4);

      const unsigned mw = (k < 2) ? mm.x : mm.y;
      const unsigned mbyte = (mw >> ((k & 1) * 16 + sh)) & 0xFFu;
      const unsigned c0 = uvA[cur].x, c1 = uvA[cur].y, c2 = uvA[cur].z, c3 = uvA[cur].w;
      const unsigned c4 = uvB[cur].x, c5 = uvB[cur].y, c6 = uvB[cur].z, c7 = uvB[cur].w;
      float w0, w1, w2, w3, w4, w5, w6, w7;
#define WCOMP(uu, jj, wdst)                                   \
      {                                                       \
        float u = __uint_as_float((uu) << 16);                \
        float v = __uint_as_float((uu) & 0xFFFF0000u);        \
        float tsel = (u > Ui) ? Ai * u : Bi * v;              \
        wdst = (mbyte & (1u << (jj))) ? tsel : 0.f;           \
      }
      WCOMP(c0, 0, w0) WCOMP(c1, 1, w1) WCOMP(c2, 2, w2) WCOMP(c3, 3, w3)
      WCOMP(c4, 4, w4) WCOMP(c5, 5, w5) WCOMP(c6, 6, w6) WCOMP(c7, 7, w7)
#undef WCOMP
      ls += ((w0 + w1) + (w2 + w3)) + ((w4 + w5) + (w6 + w7));
      union { short8 s8; unsigned u32[4]; } af;
      af.u32[0] = pack_bf2(w0, w1); af.u32[1] = pack_bf2(w2, w3);
      af.u32[2] = pack_bf2(w4, w5); af.u32[3] = pack_bf2(w6, w7);
#pragma unroll
      for (int tt = 0; tt < 8; tt++)
        acc[tt] = __builtin_amdgcn_mfma_f32_32x32x16_bf16(af.s8, b[cur][tt], acc[tt], 0, 0, 0);
    }
    mm = mmn;
  }

  ls += __shfl_xor(ls, 32);
  const size_t base = (size_t)js * (8192 * 256);
#pragma unroll
  for (int tt = 0; tt < 8; tt++) {
#pragma unroll
    for (int reg = 0; reg < 16; reg++) {
      const int row = r0 + (reg & 3) + 8 * (reg >> 2) + 4 * asel;  // verified C/D map
      const int col = tt * 32 + am;
      accP[base + (size_t)row * 256 + col] = acc[tt][reg];
    }
  }
  if (asel == 0) lP[(size_t)js * 8192 + r0 + am] = ls;
}

// ---------------- Kernel D: combine slices, normalize, ELU ------------------
__global__ __launch_bounds__(256) void combine(const float* __restrict__ accP,
                                               const float* __restrict__ lP,
                                               float* __restrict__ out, int JS) {
  const int idx = (blockIdx.x * 256 + threadIdx.x) * 4;
  const int row = idx >> 8;
  float4 s = {0.f, 0.f, 0.f, 0.f};
  float l = 0.f;
  for (int j = 0; j < JS; j++) {
    float4 a = *(const float4*)&accP[(size_t)j * (8192 * 256) + idx];
    s.x += a.x; s.y += a.y; s.z += a.z; s.w += a.w;
    l += lP[(size_t)j * 8192 + row];
  }
  float inv = 1.0f / fmaxf(l, 1e-30f);
  float vv[4] = {s.x * inv, s.y * inv, s.z * inv, s.w * inv};
  float4 o;
  o.x = vv[0] > 0.f ? vv[0] : __expf(vv[0]) - 1.f;
  o.y = vv[1] > 0.f ? vv[1] : __expf(vv[1]) - 1.f;
  o.z = vv[2] > 0.f ? vv[2] : __expf(vv[2]) - 1.f;
  o.w = vv[3] > 0.f ? vv[3] : __expf(vv[3]) - 1.f;
  *(float4*)&out[idx] = o;
}

extern "C" void kernel_launch(void* const* d_in, const int* in_sizes, int n_in,
                              void* d_out, int out_size, void* d_ws, size_t ws_size,
                              hipStream_t stream) {
  const float* h  = (const float*)d_in[0];
  const int* adj  = (const int*)d_in[1];
  const float* W  = (const float*)d_in[2];
  const float* a  = (const float*)d_in[3];
  char* ws = (char*)d_ws;
  const size_t NF = (size_t)8192 * 256;

  // JS by workspace: JS8 needs 64M accP + 4M WhT + 8M mask + smalls (~77M).
  const int JS = (ws_size >= ((size_t)78 << 20)) ? 8
               : (ws_size >= ((size_t)46 << 20)) ? 4 : 2;

  // layout: [0, JS*8M) accP (Whp 16M aliases its head, dead before attn);
  // then WhT 4M, mask 8M, smalls.
  float* Whp                = (float*)ws;
  float* accP               = (float*)ws;
  const size_t accB         = (size_t)JS * NF * 4;
  unsigned short* WhT       = (unsigned short*)(ws + accB);
  unsigned long long* maskp = (unsigned long long*)(ws + accB + ((size_t)4 << 20));
  char* sm                  = ws + accB + ((size_t)12 << 20);
  float* f1                 = (float*)sm;
  unsigned* uvpack          = (unsigned*)(sm + (32 << 10));
  unsigned* f2key           = (unsigned*)(sm + (64 << 10));
  float* lP                 = (float*)(sm + (68 << 10));

  hipMemsetAsync(f2key, 0, 4, stream);
  gemm1<<<512, 256, 0, stream>>>(h, W, Whp);
  transpose_k<<<256, 256, 0, stream>>>(Whp, WhT);
  rowstats<<<2048, 256, 0, stream>>>(Whp, a, f1, uvpack, f2key);
  adj_compress<<<2048, 256, 0, stream>>>(adj, maskp);
  if (JS == 8)
    attn_main<1024><<<2048, 64, 0, stream>>>((const unsigned char*)maskp, f1, uvpack, WhT, f2key, accP, lP);
  else if (JS == 4)
    attn_main<2048><<<1024, 64, 0, stream>>>((const unsigned char*)maskp, f1, uvpack, WhT, f2key, accP, lP);
  else
    attn_main<4096><<<512, 64, 0, stream>>>((const unsigned char*)maskp, f1, uvpack, WhT, f2key, accP, lP);
  combine<<<2048, 256, 0, stream>>>(accP, lP, (float*)d_out, JS);
}

// Round 6
// 606.021 us; speedup vs baseline: 1.0854x; 1.0812x over previous
//
#include <hip/hip_runtime.h>
#include <cstdint>
#include <cstddef>

#define ALPHA 0.2f
// N=8192, Fin=512, Fout=256 hard-coded per problem instance.

typedef __attribute__((ext_vector_type(8)))  short short8;   // 8 bf16 (4 VGPRs)
typedef __attribute__((ext_vector_type(16))) float f32x16;   // 32x32 MFMA acc

static __device__ __forceinline__ unsigned short f2bf(float x) {
  union { float f; unsigned u; } c; c.f = x;
  unsigned u = c.u;
  return (unsigned short)((u + 0x7FFFu + ((u >> 16) & 1u)) >> 16);  // RNE
}
// pack hi16(round-half-up) of two floats: result = bf(b)<<16 | bf(a)
static __device__ __forceinline__ unsigned pack_bf2(float a, float b) {
  return __builtin_amdgcn_perm(__float_as_uint(b) + 0x8000u,
                               __float_as_uint(a) + 0x8000u, 0x07060302u);
}

// ---------------- Kernel A: Whp = h @ W, K-split x2 (fp32) ------------------
__global__ __launch_bounds__(256, 2) void gemm1(const float* __restrict__ h,
                                                const float* __restrict__ W,
                                                float* __restrict__ Whp) {
  __shared__ float As[32][132];
  __shared__ float Bs[32][64];
  const int t = threadIdx.x;
  const int bid = blockIdx.x;
  const int nb = bid & 3, kb = (bid >> 2) & 1, mb = bid >> 3;
  const int m0 = mb * 128, n0 = nb * 64, kbase = kb * 256;
  const int ty = t >> 4, tx = t & 15;
  float acc[8][4];
#pragma unroll
  for (int i = 0; i < 8; i++)
#pragma unroll
    for (int j = 0; j < 4; j++) acc[i][j] = 0.f;

  for (int k0 = kbase; k0 < kbase + 256; k0 += 32) {
#pragma unroll
    for (int c = 0; c < 4; c++) {
      int m = c * 32 + (t >> 3);
      int kq = (t & 7) * 4;
      float4 v = *(const float4*)&h[(size_t)(m0 + m) * 512 + k0 + kq];
      As[kq + 0][m] = v.x; As[kq + 1][m] = v.y;
      As[kq + 2][m] = v.z; As[kq + 3][m] = v.w;
    }
#pragma unroll
    for (int c = 0; c < 2; c++) {
      int k = c * 16 + (t >> 4);
      int n = (t & 15) * 4;
      *(float4*)&Bs[k][n] = *(const float4*)&W[(size_t)(k0 + k) * 256 + n0 + n];
    }
    __syncthreads();
#pragma unroll
    for (int k = 0; k < 32; k++) {
      float4 a0 = *(float4*)&As[k][ty * 8];
      float4 a1 = *(float4*)&As[k][ty * 8 + 4];
      float4 b  = *(float4*)&Bs[k][tx * 4];
      float av[8] = {a0.x, a0.y, a0.z, a0.w, a1.x, a1.y, a1.z, a1.w};
      float bv[4] = {b.x, b.y, b.z, b.w};
#pragma unroll
      for (int i = 0; i < 8; i++)
#pragma unroll
        for (int j = 0; j < 4; j++) acc[i][j] = fmaf(av[i], bv[j], acc[i][j]);
    }
    __syncthreads();
  }
  float* dst = Whp + (size_t)kb * (8192 * 256);
#pragma unroll
  for (int i = 0; i < 8; i++) {
    float4 v = {acc[i][0], acc[i][1], acc[i][2], acc[i][3]};
    *(float4*)&dst[(size_t)(m0 + ty * 8 + i) * 256 + n0 + tx * 4] = v;
  }
}

// ------- Kernel B: per-row f1,f2 dots, u/v pack, f2max via atomicMax --------
__global__ __launch_bounds__(256) void rowstats(const float* __restrict__ Whp,
                                                const float* __restrict__ a,
                                                float* __restrict__ f1,
                                                unsigned* __restrict__ uvpack,
                                                unsigned* __restrict__ f2key) {
  const int t = threadIdx.x;
  const int w = t >> 6, lane = t & 63;
  const int i = blockIdx.x * 4 + w;
  const size_t off = (size_t)i * 256 + lane * 4;
  float4 v0 = *(const float4*)&Whp[off];
  float4 v1 = *(const float4*)&Whp[(size_t)8192 * 256 + off];
  float4 wv = {v0.x + v1.x, v0.y + v1.y, v0.z + v1.z, v0.w + v1.w};
  float4 a1 = *(const float4*)&a[lane * 4];
  float4 a2 = *(const float4*)&a[256 + lane * 4];
  float s1 = wv.x * a1.x + wv.y * a1.y + wv.z * a1.z + wv.w * a1.w;
  float s2 = wv.x * a2.x + wv.y * a2.y + wv.z * a2.z + wv.w * a2.w;
#pragma unroll
  for (int o = 32; o; o >>= 1) { s1 += __shfl_xor(s1, o); s2 += __shfl_xor(s2, o); }
  if (lane == 0) {
    f1[i] = s1;
    // u = exp(f2) in LOW 16 (consumer does pk<<16), v = exp(0.2 f2) in HIGH
    float u = __expf(s2), v = __expf(ALPHA * s2);
    uvpack[i] = (unsigned)f2bf(u) | ((unsigned)f2bf(v) << 16);
    unsigned ub = __float_as_uint(s2);
    unsigned key = (ub & 0x80000000u) ? ~ub : (ub | 0x80000000u);
    atomicMax(f2key, key);
  }
}

// ----- Kernel B2: Wtile — 32j x 256c chunks (16 KB), XOR-swizzled 16B slots -
// element (j,c) at chunk (j>>5): byte c*64 + ((jq ^ ((c>>1)&3))<<4) + (j&7)*2,
// jq=(j&31)>>3. ds_read_b128 of a (col,8j) frag then spreads all 32 banks.
__global__ __launch_bounds__(256) void transpose_k(const float* __restrict__ Whp,
                                                   unsigned short* __restrict__ Wtile) {
  const int t = threadIdx.x;                 // c
  const int j0 = blockIdx.x * 32;
  char* chunk = (char*)Wtile + (size_t)blockIdx.x * 16384;
  const float* p0 = Whp + (size_t)j0 * 256 + t;
  const float* p1 = p0 + (size_t)8192 * 256;
#pragma unroll
  for (int jq = 0; jq < 4; jq++) {
    unsigned pk[4];
#pragma unroll
    for (int x = 0; x < 4; x++) {
      float s0 = p0[(jq * 8 + 2 * x) * 256] + p1[(jq * 8 + 2 * x) * 256];
      float s1 = p0[(jq * 8 + 2 * x + 1) * 256] + p1[(jq * 8 + 2 * x + 1) * 256];
      pk[x] = pack_bf2(s0, s1);
    }
    uint4 q; q.x = pk[0]; q.y = pk[1]; q.z = pk[2]; q.w = pk[3];
    const int slot = jq ^ ((t >> 1) & 3);
    *(uint4*)(chunk + t * 64 + slot * 16) = q;
  }
}

// --------- Kernel B3: adj (int32, 268MB) -> bitmask (8MB), pure stream ------
__global__ __launch_bounds__(256) void adj_compress(const int* __restrict__ adj,
    unsigned long long* __restrict__ mask) {
  const int wave = threadIdx.x >> 6, lane = threadIdx.x & 63;
  const int row = blockIdx.x * 4 + wave;
  const int* ap = adj + (size_t)row * 8192 + lane;
  unsigned long long* mp = mask + (size_t)row * 128;
  for (int i0 = 0; i0 < 128; i0 += 8) {
    int v[8];
#pragma unroll
    for (int k = 0; k < 8; k++) v[k] = ap[(i0 + k) * 64];   // 8 loads in flight
#pragma unroll
    for (int k = 0; k < 8; k++) {
      unsigned long long m = __ballot(v[k] > 0);
      if (lane == 0) mp[i0 + k] = m;
    }
  }
}

// ---------------- Kernel C: fused masked-softmax @ Wh, LDS-shared B ---------
// Block 256 thr = 4 waves = 4 rowtiles x full 256 cols. B chunk (32j x 256c,
// 16 KB) staged in triple-buffered LDS, shared by all 4 waves -> B L2 traffic
// /32 vs R5. One barrier per chunk; staging regs prefetched 2 chunks ahead so
// the barrier's vmcnt(0) drain finds them already landed.
template <int JW>
__global__ __launch_bounds__(256, 2) void attn_main(
    const unsigned char* __restrict__ mask, const float* __restrict__ f1p,
    const unsigned* __restrict__ uvpack, const unsigned short* __restrict__ Wtile,
    const unsigned* __restrict__ f2key, float* __restrict__ accP,
    float* __restrict__ lP) {
  constexpr int JS = 8192 / JW;
  constexpr int NC = JW / 32;                 // 32-j chunks
  __shared__ unsigned uvs[JW];
  __shared__ __align__(16) char Bt[3][16384];
  const int t = threadIdx.x;
  const int w = t >> 6, lane = t & 63;
  const int am = lane & 31, asel = lane >> 5;
  const int bid = blockIdx.x;
  const int js = bid % JS, rg = bid / JS;
  const int r0 = rg * 128 + w * 32;
  const int jbase = js * JW;
  const int sh = asel * 8;

#pragma unroll
  for (int c = 0; c < JW / 1024; c++) {       // uv preload
    int idx = c * 1024 + t * 4;
    *(uint4*)&uvs[idx] = *(const uint4*)&uvpack[jbase + idx];
  }
  const char* gsrc = (const char*)Wtile + (size_t)(jbase >> 5) * 16384;
#pragma unroll
  for (int i = 0; i < 4; i++) {               // stage chunks 0,1
    uint4 v0 = *(const uint4*)(gsrc + 0 * 16384 + i * 4096 + t * 16);
    uint4 v1 = *(const uint4*)(gsrc + 1 * 16384 + i * 4096 + t * 16);
    *(uint4*)(Bt[0] + i * 4096 + t * 16) = v0;
    *(uint4*)(Bt[1] + i * 4096 + t * 16) = v1;
  }

  unsigned key = *f2key;
  unsigned ub = (key & 0x80000000u) ? (key & 0x7FFFFFFFu) : ~key;
  const float F2max = __uint_as_float(ub);
  const float f1v = f1p[r0 + am];             // row consts lane-resident
  const float x = f1v + F2max;
  const float M = x > 0.f ? x : ALPHA * x;    // analytic per-row max bound
  const float Ai = __expf(f1v - M);
  const float Bi = __expf(ALPHA * f1v - M);
  const float Ui = __expf(-f1v);              // u_j > Ui <=> f1_i + f2_j > 0

  const unsigned char* mrow = mask + (size_t)(r0 + am) * 1024 + (jbase >> 3);
  unsigned mmcur = *(const unsigned*)mrow;    // chunk 0 mask bits (32 j)
  uint4 pf[4];
  if (NC > 2) {
#pragma unroll
    for (int i = 0; i < 4; i++)
      pf[i] = *(const uint4*)(gsrc + 2 * 16384 + i * 4096 + t * 16);
  }

  f32x16 acc[8] = {};
  float ls = 0.f;
  const int slotx = (am >> 1) & 3;            // swizzle term (tt-invariant)
  __syncthreads();

  for (int g = 0; g < NC; g++) {
    if (g + 2 < NC) {                         // land prefetched chunk g+2
#pragma unroll
      for (int i = 0; i < 4; i++)
        *(uint4*)(Bt[(g + 2) % 3] + i * 4096 + t * 16) = pf[i];
    }
    if (g + 3 < NC) {                         // issue prefetch chunk g+3
#pragma unroll
      for (int i = 0; i < 4; i++)
        pf[i] = *(const uint4*)(gsrc + (size_t)(g + 3) * 16384 + i * 4096 + t * 16);
    }
    unsigned mmnext = *(const unsigned*)(mrow + (size_t)(g + 1) * 4);  // over-read ok
    const char* bb = Bt[g % 3];
#pragma unroll
    for (int kh = 0; kh < 2; kh++) {          // 2 ksteps of 16 j
      uint4 uv0 = *(const uint4*)&uvs[g * 32 + kh * 16 + asel * 8];
      uint4 uv1 = *(const uint4*)&uvs[g * 32 + kh * 16 + asel * 8 + 4];
      const unsigned mbyte = (mmcur >> (kh * 16 + sh)) & 0xFFu;
      const unsigned c0 = uv0.x, c1 = uv0.y, c2 = uv0.z, c3 = uv0.w;
      const unsigned c4 = uv1.x, c5 = uv1.y, c6 = uv1.z, c7 = uv1.w;
      float w0, w1, w2, w3, w4, w5, w6, w7;
#define WCOMP(uu, jj, wdst)                                   \
      {                                                       \
        float u = __uint_as_float((uu) << 16);                \
        float v = __uint_as_float((uu) & 0xFFFF0000u);        \
        float tsel = (u > Ui) ? Ai * u : Bi * v;              \
        wdst = (mbyte & (1u << (jj))) ? tsel : 0.f;           \
      }
      WCOMP(c0, 0, w0) WCOMP(c1, 1, w1) WCOMP(c2, 2, w2) WCOMP(c3, 3, w3)
      WCOMP(c4, 4, w4) WCOMP(c5, 5, w5) WCOMP(c6, 6, w6) WCOMP(c7, 7, w7)
#undef WCOMP
      ls += ((w0 + w1) + (w2 + w3)) + ((w4 + w5) + (w6 + w7));
      union { short8 s8; unsigned u32[4]; } af;
      af.u32[0] = pack_bf2(w0, w1); af.u32[1] = pack_bf2(w2, w3);
      af.u32[2] = pack_bf2(w4, w5); af.u32[3] = pack_bf2(w6, w7);
      const int slot = (kh * 2 + asel) ^ slotx;
      const char* baddr = bb + am * 64 + slot * 16;
#pragma unroll
      for (int tt = 0; tt < 8; tt++) {
        short8 bf = *(const short8*)(baddr + tt * 2048);
        acc[tt] = __builtin_amdgcn_mfma_f32_32x32x16_bf16(af.s8, bf, acc[tt], 0, 0, 0);
      }
    }
    mmcur = mmnext;
    __syncthreads();
  }

  ls += __shfl_xor(ls, 32);
  const size_t base = (size_t)js * (8192 * 256);
#pragma unroll
  for (int tt = 0; tt < 8; tt++) {
#pragma unroll
    for (int reg = 0; reg < 16; reg++) {
      const int row = r0 + (reg & 3) + 8 * (reg >> 2) + 4 * asel;  // verified C/D map
      const int col = tt * 32 + am;
      accP[base + (size_t)row * 256 + col] = acc[tt][reg];
    }
  }
  if (asel == 0) lP[(size_t)js * 8192 + r0 + am] = ls;
}

// ---------------- Kernel D: combine slices, normalize, ELU ------------------
__global__ __launch_bounds__(256) void combine(const float* __restrict__ accP,
                                               const float* __restrict__ lP,
                                               float* __restrict__ out, int JS) {
  const int idx = (blockIdx.x * 256 + threadIdx.x) * 4;
  const int row = idx >> 8;
  float4 s = {0.f, 0.f, 0.f, 0.f};
  float l = 0.f;
  for (int j = 0; j < JS; j++) {
    float4 a = *(const float4*)&accP[(size_t)j * (8192 * 256) + idx];
    s.x += a.x; s.y += a.y; s.z += a.z; s.w += a.w;
    l += lP[(size_t)j * 8192 + row];
  }
  float inv = 1.0f / fmaxf(l, 1e-30f);
  float vv[4] = {s.x * inv, s.y * inv, s.z * inv, s.w * inv};
  float4 o;
  o.x = vv[0] > 0.f ? vv[0] : __expf(vv[0]) - 1.f;
  o.y = vv[1] > 0.f ? vv[1] : __expf(vv[1]) - 1.f;
  o.z = vv[2] > 0.f ? vv[2] : __expf(vv[2]) - 1.f;
  o.w = vv[3] > 0.f ? vv[3] : __expf(vv[3]) - 1.f;
  *(float4*)&out[idx] = o;
}

extern "C" void kernel_launch(void* const* d_in, const int* in_sizes, int n_in,
                              void* d_out, int out_size, void* d_ws, size_t ws_size,
                              hipStream_t stream) {
  const float* h  = (const float*)d_in[0];
  const int* adj  = (const int*)d_in[1];
  const float* W  = (const float*)d_in[2];
  const float* a  = (const float*)d_in[3];
  char* ws = (char*)d_ws;
  const size_t NF = (size_t)8192 * 256;

  // JS by workspace: JS8 needs 64M accP + 4M Wtile + 8M mask + smalls (~77M).
  const int JS = (ws_size >= ((size_t)78 << 20)) ? 8 : 2;

  // layout: [0, JS*8M) accP (Whp 16M aliases its head, dead before attn);
  // then Wtile 4M, mask 8M, smalls.
  float* Whp                = (float*)ws;
  float* accP               = (float*)ws;
  const size_t accB         = (size_t)JS * NF * 4;
  unsigned short* Wtile     = (unsigned short*)(ws + accB);
  unsigned long long* maskp = (unsigned long long*)(ws + accB + ((size_t)4 << 20));
  char* sm                  = ws + accB + ((size_t)12 << 20);
  float* f1                 = (float*)sm;
  unsigned* uvpack          = (unsigned*)(sm + (32 << 10));
  unsigned* f2key           = (unsigned*)(sm + (64 << 10));
  float* lP                 = (float*)(sm + (68 << 10));

  hipMemsetAsync(f2key, 0, 4, stream);
  gemm1<<<512, 256, 0, stream>>>(h, W, Whp);
  transpose_k<<<256, 256, 0, stream>>>(Whp, Wtile);
  rowstats<<<2048, 256, 0, stream>>>(Whp, a, f1, uvpack, f2key);
  adj_compress<<<2048, 256, 0, stream>>>(adj, maskp);
  if (JS == 8)
    attn_main<1024><<<512, 256, 0, stream>>>((const unsigned char*)maskp, f1, uvpack, Wtile, f2key, accP, lP);
  else
    attn_main<4096><<<128, 256, 0, stream>>>((const unsigned char*)maskp, f1, uvpack, Wtile, f2key, accP, lP);
  combine<<<2048, 256, 0, stream>>>(accP, lP, (float*)d_out, JS);
}